// Round 2
// baseline (279.580 us; speedup 1.0000x reference)
//
#include <hip/hip_runtime.h>

#define BSZ 16
#define SSZ 8192
#define FSZ 256
#define F4  64        // FSZ/4
#define EPSV 1e-5f
#define SEGCAP 256    // actual nseg ~131 (binomial, sigma~11) -> 11-sigma margin

// --- Kernel 1: ind[s] = any_b(cp[b,s]), ind[0]=0 -------------------------
__global__ void cp_reduce_kernel(const int* __restrict__ cp, int* __restrict__ ind) {
    int s = blockIdx.x * blockDim.x + threadIdx.x;
    if (s >= SSZ) return;
    int a = 0;
#pragma unroll
    for (int b = 0; b < BSZ; ++b) a |= cp[b * SSZ + s];
    ind[s] = (s == 0) ? 0 : (a != 0 ? 1 : 0);
}

// --- Kernel 2: single-block scan -> seg_starts[], seg_id[], nseg ---------
__global__ __launch_bounds__(1024) void scan_kernel(const int* __restrict__ ind,
                                                    int* __restrict__ seg_starts,
                                                    int* __restrict__ seg_id,
                                                    int* __restrict__ nseg_out) {
    __shared__ int lds[1024];
    int t = threadIdx.x;
    int vals[8];
    int tot = 0;
#pragma unroll
    for (int i = 0; i < 8; ++i) { int v = ind[t * 8 + i]; vals[i] = v; tot += v; }
    lds[t] = tot;
    __syncthreads();
    for (int off = 1; off < 1024; off <<= 1) {
        int a = lds[t];
        int b = (t >= off) ? lds[t - off] : 0;
        __syncthreads();
        lds[t] = a + b;
        __syncthreads();
    }
    int run = lds[t] - tot;  // exclusive prefix
#pragma unroll
    for (int i = 0; i < 8; ++i) {
        int s = t * 8 + i;
        run += vals[i];
        if (vals[i]) seg_starts[run] = s;
        seg_id[s] = run;
    }
    if (t == 0) seg_starts[0] = 0;
    if (t == 1023) nseg_out[0] = lds[1023] + 1;
}

// --- Kernel 3: zero the used portion of the accumulators -----------------
__global__ void zero_kernel(float4* __restrict__ sum4, float4* __restrict__ ssq4,
                            const int* __restrict__ nseg_p) {
    int n4 = nseg_p[0] * BSZ * F4;
    int stride = gridDim.x * blockDim.x;
    float4 z = make_float4(0.f, 0.f, 0.f, 0.f);
    for (int i = blockIdx.x * blockDim.x + threadIdx.x; i < n4; i += stride) {
        sum4[i] = z;
        ssq4[i] = z;
    }
}

__device__ inline void flushacc(float* __restrict__ as, float* __restrict__ aq,
                                int seg, int b, int lane,
                                const float4& s4, const float4& q4) {
    int base = ((seg * BSZ + b) << 8) + (lane << 2);
    atomicAdd(as + base + 0, s4.x);
    atomicAdd(as + base + 1, s4.y);
    atomicAdd(as + base + 2, s4.z);
    atomicAdd(as + base + 3, s4.w);
    atomicAdd(aq + base + 0, q4.x);
    atomicAdd(aq + base + 1, q4.y);
    atomicAdd(aq + base + 2, q4.z);
    atomicAdd(aq + base + 3, q4.w);
}

// --- Kernel 4: uniform-tile stats. One WG per (b, 64-row chunk). ---------
__global__ __launch_bounds__(256) void stats_kernel(const float4* __restrict__ x4,
                                                    const int* __restrict__ seg_id,
                                                    float* __restrict__ acc_sum,
                                                    float* __restrict__ acc_ssq) {
    const int c = blockIdx.x;          // 2048 = 16 b * 128 chunks
    const int b = c >> 7;
    const int s0 = (c & 127) << 6;     // chunk base row
    const int lane = threadIdx.x & 63;
    const int wave = threadIdx.x >> 6;
    const float4* px = x4 + ((size_t)b * SSZ + s0) * F4 + lane;

    float4 sum = make_float4(0.f, 0.f, 0.f, 0.f);
    float4 ssq = make_float4(0.f, 0.f, 0.f, 0.f);
    int cur = seg_id[s0 + wave];       // first owned row's segment

#pragma unroll
    for (int h = 0; h < 2; ++h) {
        float4 v[8];
        int sid[8];
#pragma unroll
        for (int r = 0; r < 8; ++r) {
            int srow = wave + 4 * (h * 8 + r);
            v[r] = px[(size_t)srow * F4];
            sid[r] = seg_id[s0 + srow];
        }
#pragma unroll
        for (int r = 0; r < 8; ++r) {
            if (sid[r] != cur) {
                flushacc(acc_sum, acc_ssq, cur, b, lane, sum, ssq);
                sum = make_float4(0.f, 0.f, 0.f, 0.f);
                ssq = make_float4(0.f, 0.f, 0.f, 0.f);
                cur = sid[r];
            }
            sum.x += v[r].x; sum.y += v[r].y; sum.z += v[r].z; sum.w += v[r].w;
            ssq.x += v[r].x * v[r].x; ssq.y += v[r].y * v[r].y;
            ssq.z += v[r].z * v[r].z; ssq.w += v[r].w * v[r].w;
        }
    }
    flushacc(acc_sum, acc_ssq, cur, b, lane, sum, ssq);
}

// --- Kernel 5: finalize sums -> mean (in sum slot), rstd (in ssq slot) ---
__global__ void finalize_kernel(float* __restrict__ acc_sum, float* __restrict__ acc_ssq,
                                const int* __restrict__ seg_starts,
                                const int* __restrict__ nseg_p) {
    int nseg = nseg_p[0];
    int total = nseg * BSZ * FSZ;
    int stride = gridDim.x * blockDim.x;
    for (int i = blockIdx.x * blockDim.x + threadIdx.x; i < total; i += stride) {
        int seg = i >> 12;  // / (BSZ*FSZ)
        int st = seg_starts[seg];
        int en = (seg + 1 < nseg) ? seg_starts[seg + 1] : SSZ;
        float rc = 1.0f / (float)(en - st);
        float sm = acc_sum[i] * rc;
        float vv = fmaxf(acc_ssq[i] * rc - sm * sm, 0.0f);
        acc_sum[i] = sm;
        acc_ssq[i] = 1.0f / sqrtf(vv + EPSV);
    }
}

// --- Kernel 6: uniform normalize pass ------------------------------------
__global__ __launch_bounds__(256) void norm_kernel(const float4* __restrict__ x4,
                                                   const float4* __restrict__ w4p,
                                                   const float4* __restrict__ b4p,
                                                   const int* __restrict__ seg_id,
                                                   const float4* __restrict__ mean4,
                                                   const float4* __restrict__ rstd4,
                                                   float4* __restrict__ out4) {
    int tid = blockIdx.x * blockDim.x + threadIdx.x;  // [0, 524288)
    int f4 = tid & 63;
    int s = tid >> 6;  // [0, 8192)
    float4 w = w4p[f4];
    float4 bb = b4p[f4];
    int seg = seg_id[s];
    size_t xi = (size_t)s * F4 + f4;
    int mi = (seg * BSZ) * F4 + f4;
#pragma unroll
    for (int b = 0; b < BSZ; ++b) {
        float4 v = x4[xi + (size_t)b * SSZ * F4];
        float4 m = mean4[mi + b * F4];
        float4 r = rstd4[mi + b * F4];
        float4 o;
        o.x = (v.x - m.x) * r.x * w.x + bb.x;
        o.y = (v.y - m.y) * r.y * w.y + bb.y;
        o.z = (v.z - m.z) * r.z * w.z + bb.z;
        o.w = (v.w - m.w) * r.w * w.w + bb.w;
        out4[xi + (size_t)b * SSZ * F4] = o;
    }
}

extern "C" void kernel_launch(void* const* d_in, const int* in_sizes, int n_in,
                              void* d_out, int out_size, void* d_ws, size_t ws_size,
                              hipStream_t stream) {
    const float* x = (const float*)d_in[0];
    const float* w = (const float*)d_in[1];
    const float* bias = (const float*)d_in[2];
    const int* cp = (const int*)d_in[3];

    char* ws = (char*)d_ws;
    int* nseg = (int*)ws;                          // [1]
    int* seg_starts = (int*)(ws + 256);            // [SSZ]
    int* seg_id = (int*)(ws + 256 + 32768);        // [SSZ]
    int* ind = (int*)(ws + 256 + 65536);           // [SSZ]
    float* acc_sum = (float*)(ws + 131072);        // [SEGCAP*BSZ*FSZ] = 4 MB
    float* acc_ssq = acc_sum + SEGCAP * BSZ * FSZ; // 4 MB

    cp_reduce_kernel<<<(SSZ + 255) / 256, 256, 0, stream>>>(cp, ind);
    scan_kernel<<<1, 1024, 0, stream>>>(ind, seg_starts, seg_id, nseg);
    zero_kernel<<<256, 256, 0, stream>>>((float4*)acc_sum, (float4*)acc_ssq, nseg);
    stats_kernel<<<2048, 256, 0, stream>>>((const float4*)x, seg_id, acc_sum, acc_ssq);
    finalize_kernel<<<256, 256, 0, stream>>>(acc_sum, acc_ssq, seg_starts, nseg);
    norm_kernel<<<2048, 256, 0, stream>>>((const float4*)x, (const float4*)w,
                                          (const float4*)bias, seg_id,
                                          (const float4*)acc_sum, (const float4*)acc_ssq,
                                          (float4*)d_out);
}

// Round 3
// 97.672 us; speedup vs baseline: 2.8624x; 2.8624x over previous
//
#include <hip/hip_runtime.h>

#define BSZ 16
#define SSZ 8192
#define FSZ 256
#define F4  64
#define EPSV 1e-5f
#define SEGCAP 256       // ~131 expected segments, sigma ~11 -> 11-sigma cap
#define CHCAP  384       // max chunks = SSZ/CH + SEGCAP
#define CH 64

// --- Kernel 1: ind[s] = any_b(cp[b,s]), ind[0]=0 -------------------------
__global__ void cp_reduce_kernel(const int* __restrict__ cp, int* __restrict__ ind) {
    int s = blockIdx.x * blockDim.x + threadIdx.x;
    if (s >= SSZ) return;
    int a = 0;
#pragma unroll
    for (int b = 0; b < BSZ; ++b) a |= cp[b * SSZ + s];
    ind[s] = (s == 0) ? 0 : (a != 0 ? 1 : 0);
}

// --- Kernel 2: scan -> seg_starts, seg_id, chunk decomposition -----------
__global__ __launch_bounds__(1024) void scan_kernel(const int* __restrict__ ind,
                                                    int* __restrict__ seg_starts,
                                                    int* __restrict__ seg_id,
                                                    int* __restrict__ chunk_base,
                                                    int* __restrict__ chunk_seg,
                                                    int* __restrict__ meta) {
    __shared__ int lds[1024];
    __shared__ int sstart[SEGCAP];
    __shared__ int snseg;
    int t = threadIdx.x;
    int vals[8];
    int tot = 0;
#pragma unroll
    for (int i = 0; i < 8; ++i) { int v = ind[t * 8 + i]; vals[i] = v; tot += v; }
    lds[t] = tot;
    __syncthreads();
    for (int off = 1; off < 1024; off <<= 1) {
        int a = lds[t];
        int b = (t >= off) ? lds[t - off] : 0;
        __syncthreads();
        lds[t] = a + b;
        __syncthreads();
    }
    int run = lds[t] - tot;  // exclusive prefix
#pragma unroll
    for (int i = 0; i < 8; ++i) {
        int s = t * 8 + i;
        run += vals[i];
        int r = run < SEGCAP ? run : SEGCAP - 1;
        if (vals[i] && run < SEGCAP) { seg_starts[run] = s; sstart[run] = s; }
        seg_id[s] = r;
    }
    if (t == 0) { seg_starts[0] = 0; sstart[0] = 0; }
    if (t == 1023) { int n = lds[1023] + 1; snseg = n < SEGCAP ? n : SEGCAP; }
    __syncthreads();

    // phase 2: chunk decomposition (CSR over segments)
    const int nseg = snseg;
    int nch = 0;
    if (t < nseg) {
        int st = sstart[t];
        int en = (t + 1 < nseg) ? sstart[t + 1] : SSZ;
        nch = (en - st + CH - 1) / CH;
    }
    lds[t] = nch;
    __syncthreads();
    for (int off = 1; off < 1024; off <<= 1) {
        int a = lds[t];
        int b = (t >= off) ? lds[t - off] : 0;
        __syncthreads();
        lds[t] = a + b;
        __syncthreads();
    }
    int cbase = lds[t] - nch;  // exclusive prefix
    if (t < nseg) {
        chunk_base[t] = cbase;
        for (int j = 0; j < nch; ++j) chunk_seg[cbase + j] = t;
    }
    if (t == 1023) {
        chunk_base[nseg] = cbase;          // == total chunks (nch=0 here)
        meta[0] = nseg;
        meta[1] = cbase * BSZ;             // nitems
    }
}

// --- Kernel 3: balanced stats, one WG per (chunk, b), no atomics ---------
__global__ __launch_bounds__(256) void stats_kernel(const float4* __restrict__ x4,
                                                    const int* __restrict__ seg_starts,
                                                    const int* __restrict__ chunk_base,
                                                    const int* __restrict__ chunk_seg,
                                                    const int* __restrict__ meta,
                                                    float4* __restrict__ psum,
                                                    float4* __restrict__ pssq) {
    __shared__ float4 lsum[4][64];
    __shared__ float4 lssq[4][64];
    const int nitems = meta[1];
    const int nseg = meta[0];
    const int lane = threadIdx.x & 63;
    const int wave = threadIdx.x >> 6;
    for (int item = blockIdx.x; item < nitems; item += gridDim.x) {
        const int c = item >> 4;
        const int b = item & 15;
        const int seg = chunk_seg[c];
        const int j = c - chunk_base[seg];
        const int st = seg_starts[seg];
        const int en = (seg + 1 < nseg) ? seg_starts[seg + 1] : SSZ;
        const int s0 = st + j * CH;
        const int s1 = min(en, s0 + CH);
        const float4* px = x4 + (size_t)b * SSZ * F4 + lane;

        float4 sum = make_float4(0.f, 0.f, 0.f, 0.f);
        float4 ssq = make_float4(0.f, 0.f, 0.f, 0.f);
        for (int s = s0 + wave; s < s1; s += 4) {
            float4 v = px[(size_t)s * F4];
            sum.x += v.x; sum.y += v.y; sum.z += v.z; sum.w += v.w;
            ssq.x += v.x * v.x; ssq.y += v.y * v.y; ssq.z += v.z * v.z; ssq.w += v.w * v.w;
        }
        lsum[wave][lane] = sum;
        lssq[wave][lane] = ssq;
        __syncthreads();
        if (wave == 0) {
            float4 a0 = lsum[0][lane], a1 = lsum[1][lane], a2 = lsum[2][lane], a3 = lsum[3][lane];
            float4 o;
            o.x = a0.x + a1.x + a2.x + a3.x;
            o.y = a0.y + a1.y + a2.y + a3.y;
            o.z = a0.z + a1.z + a2.z + a3.z;
            o.w = a0.w + a1.w + a2.w + a3.w;
            psum[((size_t)c * BSZ + b) * F4 + lane] = o;
        } else if (wave == 1) {
            float4 a0 = lssq[0][lane], a1 = lssq[1][lane], a2 = lssq[2][lane], a3 = lssq[3][lane];
            float4 o;
            o.x = a0.x + a1.x + a2.x + a3.x;
            o.y = a0.y + a1.y + a2.y + a3.y;
            o.z = a0.z + a1.z + a2.z + a3.z;
            o.w = a0.w + a1.w + a2.w + a3.w;
            pssq[((size_t)c * BSZ + b) * F4 + lane] = o;
        }
        __syncthreads();
    }
}

// --- Kernel 4: reduce chunk partials -> mean / rstd ----------------------
__global__ __launch_bounds__(256) void finalize_kernel(const float4* __restrict__ psum,
                                                       const float4* __restrict__ pssq,
                                                       const int* __restrict__ seg_starts,
                                                       const int* __restrict__ chunk_base,
                                                       const int* __restrict__ meta,
                                                       float4* __restrict__ mean4,
                                                       float4* __restrict__ rstd4) {
    const int nseg = meta[0];
    const int total = nseg * BSZ * F4;
    const int stride = gridDim.x * blockDim.x;
    for (int i = blockIdx.x * blockDim.x + threadIdx.x; i < total; i += stride) {
        const int seg = i >> 10;
        const int b = (i >> 6) & 15;
        const int f4i = i & 63;
        const int c0 = chunk_base[seg];
        const int c1 = chunk_base[seg + 1];
        float4 s = make_float4(0.f, 0.f, 0.f, 0.f);
        float4 q = make_float4(0.f, 0.f, 0.f, 0.f);
        for (int c = c0; c < c1; ++c) {
            float4 a = psum[((size_t)c * BSZ + b) * F4 + f4i];
            float4 z = pssq[((size_t)c * BSZ + b) * F4 + f4i];
            s.x += a.x; s.y += a.y; s.z += a.z; s.w += a.w;
            q.x += z.x; q.y += z.y; q.z += z.z; q.w += z.w;
        }
        const int st = seg_starts[seg];
        const int en = (seg + 1 < nseg) ? seg_starts[seg + 1] : SSZ;
        const float rc = 1.0f / (float)(en - st);
        float4 m, r;
        m.x = s.x * rc; m.y = s.y * rc; m.z = s.z * rc; m.w = s.w * rc;
        r.x = 1.0f / sqrtf(fmaxf(q.x * rc - m.x * m.x, 0.f) + EPSV);
        r.y = 1.0f / sqrtf(fmaxf(q.y * rc - m.y * m.y, 0.f) + EPSV);
        r.z = 1.0f / sqrtf(fmaxf(q.z * rc - m.z * m.z, 0.f) + EPSV);
        r.w = 1.0f / sqrtf(fmaxf(q.w * rc - m.w * m.w, 0.f) + EPSV);
        mean4[i] = m;
        rstd4[i] = r;
    }
}

// --- Kernel 5: uniform normalize pass ------------------------------------
__global__ __launch_bounds__(256) void norm_kernel(const float4* __restrict__ x4,
                                                   const float4* __restrict__ w4p,
                                                   const float4* __restrict__ b4p,
                                                   const int* __restrict__ seg_id,
                                                   const float4* __restrict__ mean4,
                                                   const float4* __restrict__ rstd4,
                                                   float4* __restrict__ out4) {
    int tid = blockIdx.x * blockDim.x + threadIdx.x;  // 524288 = 8192 s * 64 f4
    int f4i = tid & 63;
    int s = tid >> 6;
    float4 w = w4p[f4i];
    float4 bb = b4p[f4i];
    int seg = seg_id[s];
    size_t xi = (size_t)s * F4 + f4i;
    int mi = (seg * BSZ) * F4 + f4i;
#pragma unroll
    for (int b = 0; b < BSZ; ++b) {
        float4 v = x4[xi + (size_t)b * SSZ * F4];
        float4 m = mean4[mi + b * F4];
        float4 r = rstd4[mi + b * F4];
        float4 o;
        o.x = (v.x - m.x) * r.x * w.x + bb.x;
        o.y = (v.y - m.y) * r.y * w.y + bb.y;
        o.z = (v.z - m.z) * r.z * w.z + bb.z;
        o.w = (v.w - m.w) * r.w * w.w + bb.w;
        out4[xi + (size_t)b * SSZ * F4] = o;
    }
}

extern "C" void kernel_launch(void* const* d_in, const int* in_sizes, int n_in,
                              void* d_out, int out_size, void* d_ws, size_t ws_size,
                              hipStream_t stream) {
    const float* x = (const float*)d_in[0];
    const float* w = (const float*)d_in[1];
    const float* bias = (const float*)d_in[2];
    const int* cp = (const int*)d_in[3];

    char* ws = (char*)d_ws;
    int* meta = (int*)ws;                           // [2]
    int* seg_starts = (int*)(ws + 1024);            // [SEGCAP]
    int* chunk_base = (int*)(ws + 4096);            // [SEGCAP+1]
    int* chunk_seg = (int*)(ws + 8192);             // [CHCAP]
    int* seg_id = (int*)(ws + 16384);               // [SSZ]
    int* ind = (int*)(ws + 49152);                  // [SSZ]
    float* psum = (float*)(ws + 131072);            // CHCAP*BSZ*FSZ f32 = 6.3 MB
    float* pssq = psum + (size_t)CHCAP * BSZ * FSZ;
    float* meanb = pssq + (size_t)CHCAP * BSZ * FSZ; // SEGCAP*BSZ*FSZ = 4.2 MB
    float* rstdb = meanb + (size_t)SEGCAP * BSZ * FSZ;

    cp_reduce_kernel<<<(SSZ + 255) / 256, 256, 0, stream>>>(cp, ind);
    scan_kernel<<<1, 1024, 0, stream>>>(ind, seg_starts, seg_id, chunk_base, chunk_seg, meta);
    stats_kernel<<<4096, 256, 0, stream>>>((const float4*)x, seg_starts, chunk_base,
                                           chunk_seg, meta, (float4*)psum, (float4*)pssq);
    finalize_kernel<<<512, 256, 0, stream>>>((const float4*)psum, (const float4*)pssq,
                                             seg_starts, chunk_base, meta,
                                             (float4*)meanb, (float4*)rstdb);
    norm_kernel<<<2048, 256, 0, stream>>>((const float4*)x, (const float4*)w,
                                          (const float4*)bias, seg_id,
                                          (const float4*)meanb, (const float4*)rstdb,
                                          (float4*)d_out);
}

// Round 5
// 95.894 us; speedup vs baseline: 2.9155x; 1.0185x over previous
//
#include <hip/hip_runtime.h>

#define BSZ 16
#define SSZ 8192
#define FSZ 256
#define F4  64
#define EPSV 1e-5f
#define SEGCAP 256       // ~131 expected segments, sigma ~11 -> 11-sigma cap
#define CHCAP  384       // max chunks = SSZ/CH + SEGCAP
#define CH 64

typedef float f32x4 __attribute__((ext_vector_type(4)));

// --- Kernel 1: ind[s] = any_b(cp[b,s]), ind[0]=0 -------------------------
__global__ void cp_reduce_kernel(const int* __restrict__ cp, int* __restrict__ ind) {
    int s = blockIdx.x * blockDim.x + threadIdx.x;
    if (s >= SSZ) return;
    int a = 0;
#pragma unroll
    for (int b = 0; b < BSZ; ++b) a |= cp[b * SSZ + s];
    ind[s] = (s == 0) ? 0 : (a != 0 ? 1 : 0);
}

// --- Kernel 2: scan -> seg_starts, seg_id, chunk decomposition -----------
__global__ __launch_bounds__(1024) void scan_kernel(const int* __restrict__ ind,
                                                    int* __restrict__ seg_starts,
                                                    int* __restrict__ seg_id,
                                                    int* __restrict__ chunk_base,
                                                    int* __restrict__ chunk_seg,
                                                    int* __restrict__ meta) {
    __shared__ int lds[1024];
    __shared__ int sstart[SEGCAP];
    __shared__ int snseg;
    int t = threadIdx.x;
    int vals[8];
    int tot = 0;
#pragma unroll
    for (int i = 0; i < 8; ++i) { int v = ind[t * 8 + i]; vals[i] = v; tot += v; }
    lds[t] = tot;
    __syncthreads();
    for (int off = 1; off < 1024; off <<= 1) {
        int a = lds[t];
        int b = (t >= off) ? lds[t - off] : 0;
        __syncthreads();
        lds[t] = a + b;
        __syncthreads();
    }
    int run = lds[t] - tot;  // exclusive prefix
#pragma unroll
    for (int i = 0; i < 8; ++i) {
        int s = t * 8 + i;
        run += vals[i];
        int r = run < SEGCAP ? run : SEGCAP - 1;
        if (vals[i] && run < SEGCAP) { seg_starts[run] = s; sstart[run] = s; }
        seg_id[s] = r;
    }
    if (t == 0) { seg_starts[0] = 0; sstart[0] = 0; }
    if (t == 1023) { int n = lds[1023] + 1; snseg = n < SEGCAP ? n : SEGCAP; }
    __syncthreads();

    // phase 2: chunk decomposition (CSR over segments)
    const int nseg = snseg;
    int nch = 0;
    if (t < nseg) {
        int st = sstart[t];
        int en = (t + 1 < nseg) ? sstart[t + 1] : SSZ;
        nch = (en - st + CH - 1) / CH;
    }
    lds[t] = nch;
    __syncthreads();
    for (int off = 1; off < 1024; off <<= 1) {
        int a = lds[t];
        int b = (t >= off) ? lds[t - off] : 0;
        __syncthreads();
        lds[t] = a + b;
        __syncthreads();
    }
    int cbase = lds[t] - nch;  // exclusive prefix
    if (t < nseg) {
        chunk_base[t] = cbase;
        for (int j = 0; j < nch; ++j) chunk_seg[cbase + j] = t;
    }
    if (t == 1023) {
        chunk_base[nseg] = cbase;          // == total chunks (t>=nseg so nch=0)
        meta[0] = nseg;
        meta[1] = cbase * BSZ;             // nitems
    }
}

// --- Kernel 3: balanced stats, one WG per (chunk, b), no atomics ---------
__global__ __launch_bounds__(256) void stats_kernel(const f32x4* __restrict__ x4,
                                                    const int* __restrict__ seg_starts,
                                                    const int* __restrict__ chunk_base,
                                                    const int* __restrict__ chunk_seg,
                                                    const int* __restrict__ meta,
                                                    f32x4* __restrict__ psum,
                                                    f32x4* __restrict__ pssq) {
    __shared__ f32x4 lsum[4][64];
    __shared__ f32x4 lssq[4][64];
    const int nitems = meta[1];
    const int nseg = meta[0];
    const int lane = threadIdx.x & 63;
    const int wave = threadIdx.x >> 6;
    for (int item = blockIdx.x; item < nitems; item += gridDim.x) {
        const int c = item >> 4;
        const int b = item & 15;
        const int seg = chunk_seg[c];
        const int j = c - chunk_base[seg];
        const int st = seg_starts[seg];
        const int en = (seg + 1 < nseg) ? seg_starts[seg + 1] : SSZ;
        const int s0 = st + j * CH;
        const int s1 = min(en, s0 + CH);
        const f32x4* px = x4 + (size_t)b * SSZ * F4 + lane;

        f32x4 sum = {0.f, 0.f, 0.f, 0.f};
        f32x4 ssq = {0.f, 0.f, 0.f, 0.f};
        for (int s = s0 + wave; s < s1; s += 4) {
            f32x4 v = px[(size_t)s * F4];
            sum += v;
            ssq += v * v;
        }
        lsum[wave][lane] = sum;
        lssq[wave][lane] = ssq;
        __syncthreads();
        if (wave == 0) {
            f32x4 o = lsum[0][lane] + lsum[1][lane] + lsum[2][lane] + lsum[3][lane];
            __builtin_nontemporal_store(o, &psum[((size_t)c * BSZ + b) * F4 + lane]);
        } else if (wave == 1) {
            f32x4 o = lssq[0][lane] + lssq[1][lane] + lssq[2][lane] + lssq[3][lane];
            __builtin_nontemporal_store(o, &pssq[((size_t)c * BSZ + b) * F4 + lane]);
        }
        __syncthreads();
    }
}

// --- Kernel 4: reduce chunk partials -> mean / rstd ----------------------
__global__ __launch_bounds__(256) void finalize_kernel(const f32x4* __restrict__ psum,
                                                       const f32x4* __restrict__ pssq,
                                                       const int* __restrict__ seg_starts,
                                                       const int* __restrict__ chunk_base,
                                                       const int* __restrict__ meta,
                                                       f32x4* __restrict__ mean4,
                                                       f32x4* __restrict__ rstd4) {
    const int nseg = meta[0];
    const int total = nseg * BSZ * F4;
    const int stride = gridDim.x * blockDim.x;
    for (int i = blockIdx.x * blockDim.x + threadIdx.x; i < total; i += stride) {
        const int seg = i >> 10;
        const int b = (i >> 6) & 15;
        const int f4i = i & 63;
        const int c0 = chunk_base[seg];
        const int c1 = chunk_base[seg + 1];
        f32x4 s = {0.f, 0.f, 0.f, 0.f};
        f32x4 q = {0.f, 0.f, 0.f, 0.f};
        for (int c = c0; c < c1; ++c) {
            s += __builtin_nontemporal_load(&psum[((size_t)c * BSZ + b) * F4 + f4i]);
            q += __builtin_nontemporal_load(&pssq[((size_t)c * BSZ + b) * F4 + f4i]);
        }
        const int st = seg_starts[seg];
        const int en = (seg + 1 < nseg) ? seg_starts[seg + 1] : SSZ;
        const float rc = 1.0f / (float)(en - st);
        f32x4 m = s * rc;
        f32x4 var = q * rc - m * m;
        f32x4 r;
        r.x = 1.0f / sqrtf(fmaxf(var.x, 0.f) + EPSV);
        r.y = 1.0f / sqrtf(fmaxf(var.y, 0.f) + EPSV);
        r.z = 1.0f / sqrtf(fmaxf(var.z, 0.f) + EPSV);
        r.w = 1.0f / sqrtf(fmaxf(var.w, 0.f) + EPSV);
        mean4[i] = m;
        rstd4[i] = r;
    }
}

// --- Kernel 5: uniform normalize pass, nontemporal output ----------------
__global__ __launch_bounds__(256) void norm_kernel(const f32x4* __restrict__ x4,
                                                   const f32x4* __restrict__ w4p,
                                                   const f32x4* __restrict__ b4p,
                                                   const int* __restrict__ seg_id,
                                                   const f32x4* __restrict__ mean4,
                                                   const f32x4* __restrict__ rstd4,
                                                   f32x4* __restrict__ out4) {
    int tid = blockIdx.x * blockDim.x + threadIdx.x;  // 524288 = 8192 s * 64 f4
    int f4i = tid & 63;
    int s = tid >> 6;
    f32x4 w = w4p[f4i];
    f32x4 bb = b4p[f4i];
    int seg = seg_id[s];
    size_t xi = (size_t)s * F4 + f4i;
    int mi = (seg * BSZ) * F4 + f4i;
#pragma unroll
    for (int b = 0; b < BSZ; ++b) {
        f32x4 v = x4[xi + (size_t)b * SSZ * F4];
        f32x4 m = mean4[mi + b * F4];
        f32x4 r = rstd4[mi + b * F4];
        f32x4 o = (v - m) * r * w + bb;
        __builtin_nontemporal_store(o, &out4[xi + (size_t)b * SSZ * F4]);
    }
}

extern "C" void kernel_launch(void* const* d_in, const int* in_sizes, int n_in,
                              void* d_out, int out_size, void* d_ws, size_t ws_size,
                              hipStream_t stream) {
    const f32x4* x = (const f32x4*)d_in[0];
    const f32x4* w = (const f32x4*)d_in[1];
    const f32x4* bias = (const f32x4*)d_in[2];
    const int* cp = (const int*)d_in[3];

    char* ws = (char*)d_ws;
    int* meta = (int*)ws;                           // [2]
    int* seg_starts = (int*)(ws + 1024);            // [SEGCAP]
    int* chunk_base = (int*)(ws + 4096);            // [SEGCAP+1]
    int* chunk_seg = (int*)(ws + 8192);             // [CHCAP]
    int* seg_id = (int*)(ws + 16384);               // [SSZ]
    int* ind = (int*)(ws + 49152);                  // [SSZ]
    f32x4* psum = (f32x4*)(ws + 131072);            // CHCAP*BSZ*FSZ f32 = 6.3 MB
    f32x4* pssq = psum + (size_t)CHCAP * BSZ * F4;
    f32x4* mean4 = pssq + (size_t)CHCAP * BSZ * F4; // SEGCAP*BSZ*FSZ = 4.2 MB
    f32x4* rstd4 = mean4 + (size_t)SEGCAP * BSZ * F4;

    cp_reduce_kernel<<<(SSZ + 255) / 256, 256, 0, stream>>>(cp, ind);
    scan_kernel<<<1, 1024, 0, stream>>>(ind, seg_starts, seg_id, chunk_base, chunk_seg, meta);
    stats_kernel<<<4096, 256, 0, stream>>>(x, seg_starts, chunk_base,
                                           chunk_seg, meta, psum, pssq);
    finalize_kernel<<<512, 256, 0, stream>>>(psum, pssq, seg_starts, chunk_base, meta,
                                             mean4, rstd4);
    norm_kernel<<<2048, 256, 0, stream>>>(x, w, bias, seg_id, mean4, rstd4,
                                          (f32x4*)d_out);
}